// Round 1
// baseline (1104.908 us; speedup 1.0000x reference)
//
#include <hip/hip_runtime.h>
#include <math.h>

#define DIM  768
#define NH   12
#define HD   64
#define BATCH 2
#define NQ   2048
#define NKV  2048
#define QSCALE 0.125f   // 64^-0.5

// ---------------------------------------------------------------------------
// kc = latent_k @ Wk_c   (768-vector x 768x768)
// ---------------------------------------------------------------------------
__global__ void kc_kernel(const float* __restrict__ latent,
                          const float* __restrict__ Wkc,
                          float* __restrict__ kc) {
    int j = blockIdx.x * blockDim.x + threadIdx.x;
    if (j >= DIM) return;
    float acc = 0.f;
    for (int i = 0; i < DIM; ++i) acc += latent[i] * Wkc[i * DIM + j];
    kc[j] = acc;
}

// ---------------------------------------------------------------------------
// Fused GEMM: C[M=4096][768] = sum_p A_p @ W_p  (+ bias broadcast over rows)
// A row-major [4096][768], W row-major [768][768]
// 64x64 block tile, BK=16, 256 threads, 4x4 microtile per thread
// ---------------------------------------------------------------------------
#define BM 64
#define BN 64
#define BK 16

__global__ __launch_bounds__(256)
void gemm3_kernel(const float* __restrict__ A0, const float* __restrict__ W0,
                  const float* __restrict__ A1, const float* __restrict__ W1,
                  const float* __restrict__ A2, const float* __restrict__ W2,
                  const float* __restrict__ bias,
                  float* __restrict__ C) {
    __shared__ float As[BK][BM + 1];   // As[k][m], pad -> conflict-free
    __shared__ float Ws[BK][BN];       // Ws[k][n], float4 friendly

    const int tid = threadIdx.x;
    const int tx = tid & 15;           // output col group
    const int ty = tid >> 4;           // output row group
    const int m0 = blockIdx.y * BM;
    const int n0 = blockIdx.x * BN;

    const int ml = tid >> 2;           // 0..63  A-tile row
    const int k4 = (tid & 3) * 4;      // 0,4,8,12 A-tile col quad
    const int kl = tid >> 4;           // 0..15  W-tile row
    const int n4 = (tid & 15) * 4;     // W-tile col quad

    float acc[4][4] = {};

    const float* Alist[3] = {A0, A1, A2};
    const float* Wlist[3] = {W0, W1, W2};

    for (int p = 0; p < 3; ++p) {
        const float* A = Alist[p];
        const float* W = Wlist[p];
        if (A == nullptr) continue;
        for (int k0 = 0; k0 < DIM; k0 += BK) {
            float4 av = *(const float4*)(A + (size_t)(m0 + ml) * DIM + k0 + k4);
            float4 wv = *(const float4*)(W + (size_t)(k0 + kl) * DIM + n0 + n4);
            __syncthreads();            // previous tile's reads complete
            As[k4 + 0][ml] = av.x;
            As[k4 + 1][ml] = av.y;
            As[k4 + 2][ml] = av.z;
            As[k4 + 3][ml] = av.w;
            *(float4*)(&Ws[kl][n4]) = wv;
            __syncthreads();            // tile visible
            #pragma unroll
            for (int kk = 0; kk < BK; ++kk) {
                float ar[4];
                #pragma unroll
                for (int i = 0; i < 4; ++i) ar[i] = As[kk][ty * 4 + i];
                float4 b = *(const float4*)(&Ws[kk][tx * 4]);
                float br[4] = {b.x, b.y, b.z, b.w};
                #pragma unroll
                for (int i = 0; i < 4; ++i)
                    #pragma unroll
                    for (int j = 0; j < 4; ++j)
                        acc[i][j] = fmaf(ar[i], br[j], acc[i][j]);
            }
        }
    }

    float bv[4] = {0.f, 0.f, 0.f, 0.f};
    if (bias != nullptr) {
        #pragma unroll
        for (int j = 0; j < 4; ++j) bv[j] = bias[n0 + tx * 4 + j];
    }
    #pragma unroll
    for (int i = 0; i < 4; ++i) {
        float4 r;
        r.x = acc[i][0] + bv[0];
        r.y = acc[i][1] + bv[1];
        r.z = acc[i][2] + bv[2];
        r.w = acc[i][3] + bv[3];
        *(float4*)(C + (size_t)(m0 + ty * 4 + i) * DIM + n0 + tx * 4) = r;
    }
}

// ---------------------------------------------------------------------------
// Flash attention (fp32): per (b,h), per 64-row Q block, stream 64-row KV tiles
// Q/K/V layout: [B][N][768] with head h at cols h*64..h*64+63
// ---------------------------------------------------------------------------
__global__ __launch_bounds__(256)
void flash_kernel(const float* __restrict__ Q, const float* __restrict__ K,
                  const float* __restrict__ V, float* __restrict__ O) {
    __shared__ float Qs[64][65];
    __shared__ float Ks[64][65];
    __shared__ float Vs[64][65];
    __shared__ float Ps[64][65];

    const int tid = threadIdx.x;
    const int tx = tid & 15;
    const int ty = tid >> 4;
    const int q0 = blockIdx.x * 64;
    const int bh = blockIdx.y;
    const int b  = bh / NH;
    const int h  = bh % NH;

    const float* Qbase = Q + ((size_t)b * NQ + q0) * DIM + h * HD;
    const float* Kbase = K + (size_t)b * NKV * DIM + h * HD;
    const float* Vbase = V + (size_t)b * NKV * DIM + h * HD;

    // load + pre-scale Q tile
    {
        const int r  = tid >> 2;
        const int c0 = (tid & 3) * 16;
        #pragma unroll
        for (int u = 0; u < 4; ++u) {
            float4 v = *(const float4*)(Qbase + (size_t)r * DIM + c0 + u * 4);
            Qs[r][c0 + u * 4 + 0] = v.x * QSCALE;
            Qs[r][c0 + u * 4 + 1] = v.y * QSCALE;
            Qs[r][c0 + u * 4 + 2] = v.z * QSCALE;
            Qs[r][c0 + u * 4 + 3] = v.w * QSCALE;
        }
    }

    float o[4][4] = {};
    float mrow[4] = {-INFINITY, -INFINITY, -INFINITY, -INFINITY};
    float lrow[4] = {0.f, 0.f, 0.f, 0.f};

    for (int t0 = 0; t0 < NKV; t0 += 64) {
        // stage K/V tiles
        {
            const int r  = tid >> 2;
            const int c0 = (tid & 3) * 16;
            float4 kv[4], vv[4];
            #pragma unroll
            for (int u = 0; u < 4; ++u) {
                kv[u] = *(const float4*)(Kbase + (size_t)(t0 + r) * DIM + c0 + u * 4);
                vv[u] = *(const float4*)(Vbase + (size_t)(t0 + r) * DIM + c0 + u * 4);
            }
            __syncthreads();   // previous PV reads complete
            #pragma unroll
            for (int u = 0; u < 4; ++u) {
                Ks[r][c0 + u * 4 + 0] = kv[u].x;
                Ks[r][c0 + u * 4 + 1] = kv[u].y;
                Ks[r][c0 + u * 4 + 2] = kv[u].z;
                Ks[r][c0 + u * 4 + 3] = kv[u].w;
                Vs[r][c0 + u * 4 + 0] = vv[u].x;
                Vs[r][c0 + u * 4 + 1] = vv[u].y;
                Vs[r][c0 + u * 4 + 2] = vv[u].z;
                Vs[r][c0 + u * 4 + 3] = vv[u].w;
            }
            __syncthreads();   // tiles (and on iter 0, Qs) visible
        }

        // S = Qs . Ks^T  (4x4 per thread)
        float s[4][4] = {};
        #pragma unroll 4
        for (int d = 0; d < 64; ++d) {
            float qr[4], kr[4];
            #pragma unroll
            for (int i = 0; i < 4; ++i) qr[i] = Qs[ty * 4 + i][d];
            #pragma unroll
            for (int j = 0; j < 4; ++j) kr[j] = Ks[tx * 4 + j][d];
            #pragma unroll
            for (int i = 0; i < 4; ++i)
                #pragma unroll
                for (int j = 0; j < 4; ++j)
                    s[i][j] = fmaf(qr[i], kr[j], s[i][j]);
        }

        // online softmax per row (rows ty*4+i; reduce across 16 tx lanes)
        #pragma unroll
        for (int i = 0; i < 4; ++i) {
            float mx = fmaxf(fmaxf(s[i][0], s[i][1]), fmaxf(s[i][2], s[i][3]));
            mx = fmaxf(mx, __shfl_xor(mx, 1));
            mx = fmaxf(mx, __shfl_xor(mx, 2));
            mx = fmaxf(mx, __shfl_xor(mx, 4));
            mx = fmaxf(mx, __shfl_xor(mx, 8));
            float mnew = fmaxf(mrow[i], mx);
            float sc   = __expf(mrow[i] - mnew);
            float rs = 0.f;
            #pragma unroll
            for (int j = 0; j < 4; ++j) {
                float p = __expf(s[i][j] - mnew);
                s[i][j] = p;
                rs += p;
            }
            rs += __shfl_xor(rs, 1);
            rs += __shfl_xor(rs, 2);
            rs += __shfl_xor(rs, 4);
            rs += __shfl_xor(rs, 8);
            lrow[i] = lrow[i] * sc + rs;
            mrow[i] = mnew;
            #pragma unroll
            for (int j = 0; j < 4; ++j) o[i][j] *= sc;
        }

        // publish P
        #pragma unroll
        for (int i = 0; i < 4; ++i)
            #pragma unroll
            for (int j = 0; j < 4; ++j)
                Ps[ty * 4 + i][tx * 4 + j] = s[i][j];
        __syncthreads();

        // O += P . V
        #pragma unroll 4
        for (int j2 = 0; j2 < 64; ++j2) {
            float pr[4], vr[4];
            #pragma unroll
            for (int i = 0; i < 4; ++i) pr[i] = Ps[ty * 4 + i][j2];
            #pragma unroll
            for (int c = 0; c < 4; ++c) vr[c] = Vs[j2][tx * 4 + c];
            #pragma unroll
            for (int i = 0; i < 4; ++i)
                #pragma unroll
                for (int c = 0; c < 4; ++c)
                    o[i][c] = fmaf(pr[i], vr[c], o[i][c]);
        }
        __syncthreads();   // PV done before next tile overwrite
    }

    #pragma unroll
    for (int i = 0; i < 4; ++i) {
        float inv = 1.f / lrow[i];
        float4 r;
        r.x = o[i][0] * inv;
        r.y = o[i][1] * inv;
        r.z = o[i][2] * inv;
        r.w = o[i][3] * inv;
        *(float4*)(O + ((size_t)b * NQ + q0 + ty * 4 + i) * DIM + h * HD + tx * 4) = r;
    }
}

// ---------------------------------------------------------------------------
extern "C" void kernel_launch(void* const* d_in, const int* in_sizes, int n_in,
                              void* d_out, int out_size, void* d_ws, size_t ws_size,
                              hipStream_t stream) {
    const float* words   = (const float*)d_in[0];
    const float* posw    = (const float*)d_in[1];
    const float* consc   = (const float*)d_in[2];
    const float* cross   = (const float*)d_in[3];
    const float* pcross  = (const float*)d_in[4];
    const float* Wq_w    = (const float*)d_in[5];
    const float* Wk_w    = (const float*)d_in[6];
    const float* Wv_w    = (const float*)d_in[7];
    const float* Wq_p    = (const float*)d_in[8];
    const float* Wk_p    = (const float*)d_in[9];
    const float* Wq_c    = (const float*)d_in[10];
    const float* Wk_c    = (const float*)d_in[11];
    const float* latentk = (const float*)d_in[12];
    const float* Wo      = (const float*)d_in[13];
    const float* bo      = (const float*)d_in[14];

    const size_t MTOT = (size_t)BATCH * NQ;          // 4096
    const size_t MAT  = MTOT * DIM;                  // 3,145,728 floats

    float* ws  = (float*)d_ws;
    float* Qw  = ws;
    float* Kw  = ws + MAT;
    float* Vw  = ws + 2 * MAT;
    float* AO  = ws + 3 * MAT;
    float* kcv = ws + 4 * MAT;

    // kc = latent_k @ Wk_c
    kc_kernel<<<dim3(3), dim3(256), 0, stream>>>(latentk, Wk_c, kcv);

    // Q = words@Wq_w + position_words@Wq_p + conscious_words@Wq_c
    gemm3_kernel<<<dim3(DIM / BN, MTOT / BM), dim3(256), 0, stream>>>(
        words, Wq_w, posw, Wq_p, consc, Wq_c, nullptr, Qw);

    // K = cross_kv@Wk_w + position_cross@Wk_p + kc
    gemm3_kernel<<<dim3(DIM / BN, MTOT / BM), dim3(256), 0, stream>>>(
        cross, Wk_w, pcross, Wk_p, nullptr, nullptr, kcv, Kw);

    // V = cross_kv@Wv_w
    gemm3_kernel<<<dim3(DIM / BN, MTOT / BM), dim3(256), 0, stream>>>(
        cross, Wv_w, nullptr, nullptr, nullptr, nullptr, nullptr, Vw);

    // flash attention -> AO  (merged-head layout [b][n][h*64+d])
    flash_kernel<<<dim3(NQ / 64, BATCH * NH), dim3(256), 0, stream>>>(Qw, Kw, Vw, AO);

    // out = AO @ Wo + bo
    gemm3_kernel<<<dim3(DIM / BN, MTOT / BM), dim3(256), 0, stream>>>(
        AO, Wo, nullptr, nullptr, nullptr, nullptr, bo, (float*)d_out);
}

// Round 2
// 233.055 us; speedup vs baseline: 4.7410x; 4.7410x over previous
//
#include <hip/hip_runtime.h>
#include <math.h>

#define DIM  768
#define NH   12
#define HD   64
#define BATCH 2
#define NQ   2048
#define NKV  2048
#define QSCALE 0.125f

typedef short bf16x8 __attribute__((ext_vector_type(8)));
typedef float f32x4  __attribute__((ext_vector_type(4)));

// fp32 -> bf16 round-to-nearest-even
__device__ __forceinline__ unsigned short f2bf(float f) {
    unsigned u = __float_as_uint(f);
    unsigned r = (u + 0x7FFFu + ((u >> 16) & 1u)) >> 16;
    return (unsigned short)r;
}

// async global->LDS 16B copy; lds must be the WAVE-UNIFORM base (HW adds lane*16)
__device__ __forceinline__ void ld_lds16(void* lds, const void* g) {
    __builtin_amdgcn_global_load_lds(
        (const __attribute__((address_space(1))) unsigned int*)g,
        (__attribute__((address_space(3))) unsigned int*)lds, 16, 0, 0);
}

// ---------------------------------------------------------------------------
// kc = latent_k @ Wk_c  (fp32)
// ---------------------------------------------------------------------------
__global__ void kc_kernel(const float* __restrict__ latent,
                          const float* __restrict__ Wkc,
                          float* __restrict__ kc) {
    int j = blockIdx.x * blockDim.x + threadIdx.x;
    if (j >= DIM) return;
    float acc = 0.f;
    for (int i = 0; i < DIM; ++i) acc += latent[i] * Wkc[i * DIM + j];
    kc[j] = acc;
}

// ---------------------------------------------------------------------------
// fp32 -> bf16 elementwise, up to 4 tensors selected by blockIdx.y
// each tensor: 4096*768 = 3,145,728 elems; grid (3072, ntensors), 256 thr
// ---------------------------------------------------------------------------
__global__ __launch_bounds__(256)
void convert_acts(const float* __restrict__ s0, const float* __restrict__ s1,
                  const float* __restrict__ s2, const float* __restrict__ s3,
                  unsigned short* __restrict__ dst) {
    const float* srcs[4] = {s0, s1, s2, s3};
    const float* s = srcs[blockIdx.y];
    size_t i = ((size_t)blockIdx.x * 256 + threadIdx.x) * 4;
    float4 v = *(const float4*)(s + i);
    ushort4 o;
    o.x = f2bf(v.x); o.y = f2bf(v.y); o.z = f2bf(v.z); o.w = f2bf(v.w);
    *(ushort4*)(dst + (size_t)blockIdx.y * 3145728 + i) = o;
}

// ---------------------------------------------------------------------------
// weight transpose+convert: W fp32 [768][768] -> Wt bf16 [n][k]
// grid (24,24,7), block 256
// ---------------------------------------------------------------------------
__global__ __launch_bounds__(256)
void conv_w(const float* __restrict__ w0, const float* __restrict__ w1,
            const float* __restrict__ w2, const float* __restrict__ w3,
            const float* __restrict__ w4, const float* __restrict__ w5,
            const float* __restrict__ w6, unsigned short* __restrict__ dst) {
    __shared__ float t[32][33];
    const float* Ws[7] = {w0, w1, w2, w3, w4, w5, w6};
    const float* W = Ws[blockIdx.z];
    unsigned short* D = dst + (size_t)blockIdx.z * (768 * 768);
    int r0 = blockIdx.y * 32, c0 = blockIdx.x * 32;
    int tx = threadIdx.x & 31, ty = threadIdx.x >> 5;
    #pragma unroll
    for (int yy = 0; yy < 4; ++yy)
        t[ty * 4 + yy][tx] = W[(size_t)(r0 + ty * 4 + yy) * 768 + c0 + tx];
    __syncthreads();
    #pragma unroll
    for (int yy = 0; yy < 4; ++yy)
        D[(size_t)(c0 + ty * 4 + yy) * 768 + r0 + tx] = f2bf(t[tx][ty * 4 + yy]);
}

// ---------------------------------------------------------------------------
// V bf16 [4096][768] -> Vt bf16 [b][768][2048]
// grid (24, 64, 2), block 256
// ---------------------------------------------------------------------------
__global__ __launch_bounds__(256)
void vt_kernel(const unsigned short* __restrict__ V, unsigned short* __restrict__ Vt) {
    __shared__ unsigned short t[32][33];
    int b = blockIdx.z;
    int c0 = blockIdx.x * 32;   // d col
    int n0 = blockIdx.y * 32;   // seq row
    int tx = threadIdx.x & 31, ty = threadIdx.x >> 5;
    #pragma unroll
    for (int yy = 0; yy < 4; ++yy)
        t[ty * 4 + yy][tx] = V[(size_t)(b * 2048 + n0 + ty * 4 + yy) * 768 + c0 + tx];
    __syncthreads();
    #pragma unroll
    for (int yy = 0; yy < 4; ++yy)
        Vt[(size_t)(b * 768 + c0 + ty * 4 + yy) * 2048 + n0 + tx] = t[tx][ty * 4 + yy];
}

// ---------------------------------------------------------------------------
// MFMA GEMM: C[4096][768] = sum_p A_p @ W_p (+bias)
// A bf16 [4096][768] row-major, W supplied TRANSPOSED bf16 [n][k].
// Tile 64(M) x 128(N), BK=64, 256 threads / 4 waves; wave w covers n-range
// w*32, full 64 rows; frags 4(m) x 2(n) of 16x16, 2 K-chunks per step.
// LDS rows are 128B; XOR-swizzle byte^=(row&7)<<4 via pre-swizzled source.
// ---------------------------------------------------------------------------
template<int NPAIR, bool OUTF32>
__global__ __launch_bounds__(256)
void mfma_gemm(const unsigned short* __restrict__ A0, const unsigned short* __restrict__ B0,
               const unsigned short* __restrict__ A1, const unsigned short* __restrict__ B1,
               const unsigned short* __restrict__ A2, const unsigned short* __restrict__ B2,
               const float* __restrict__ bias, void* __restrict__ Cout) {
    __shared__ unsigned short As[64 * 64];    // 8 KB
    __shared__ unsigned short Bs[128 * 64];   // 16 KB
    const int tid = threadIdx.x;
    const int w = tid >> 6, l = tid & 63, g = l >> 4, r16 = l & 15;
    const int n0 = blockIdx.x * 128, m0 = blockIdx.y * 64;

    const unsigned short* Alist[3] = {A0, A1, A2};
    const unsigned short* Blist[3] = {B0, B1, B2};

    f32x4 acc[4][2];
    #pragma unroll
    for (int i = 0; i < 4; ++i)
        #pragma unroll
        for (int j = 0; j < 2; ++j) acc[i][j] = (f32x4){0.f, 0.f, 0.f, 0.f};

    #pragma unroll 1
    for (int p = 0; p < NPAIR; ++p) {
        const unsigned short* A = Alist[p];
        const unsigned short* B = Blist[p];
        for (int k0 = 0; k0 < 768; k0 += 64) {
            __syncthreads();   // prior compute reads done
            #pragma unroll
            for (int is = 0; is < 2; ++is) {
                int c = is * 256 + tid, r = c >> 3, cc = c & 7;
                int col = ((cc ^ (r & 7)) << 3);
                ld_lds16((char*)As + is * 4096 + w * 1024,
                         A + (size_t)(m0 + r) * 768 + k0 + col);
            }
            #pragma unroll
            for (int is = 0; is < 4; ++is) {
                int c = is * 256 + tid, r = c >> 3, cc = c & 7;
                int col = ((cc ^ (r & 7)) << 3);
                ld_lds16((char*)Bs + is * 4096 + w * 1024,
                         B + (size_t)(n0 + r) * 768 + k0 + col);
            }
            __syncthreads();   // drains vmcnt -> tiles visible
            #pragma unroll
            for (int kk = 0; kk < 2; ++kk) {
                bf16x8 af[4], bf[2];
                #pragma unroll
                for (int i = 0; i < 4; ++i) {
                    int row = i * 16 + r16;
                    af[i] = *(const bf16x8*)((const char*)As + row * 128 +
                              ((kk * 64 + g * 16) ^ ((row & 7) << 4)));
                }
                #pragma unroll
                for (int j = 0; j < 2; ++j) {
                    int row = w * 32 + j * 16 + r16;
                    bf[j] = *(const bf16x8*)((const char*)Bs + row * 128 +
                              ((kk * 64 + g * 16) ^ ((row & 7) << 4)));
                }
                #pragma unroll
                for (int i = 0; i < 4; ++i)
                    #pragma unroll
                    for (int j = 0; j < 2; ++j)
                        acc[i][j] = __builtin_amdgcn_mfma_f32_16x16x32_bf16(
                            af[i], bf[j], acc[i][j], 0, 0, 0);
            }
        }
    }

    #pragma unroll
    for (int i = 0; i < 4; ++i) {
        #pragma unroll
        for (int j = 0; j < 2; ++j) {
            int col = n0 + w * 32 + j * 16 + r16;
            float bv = bias ? bias[col] : 0.f;
            #pragma unroll
            for (int rr = 0; rr < 4; ++rr) {
                int row = m0 + i * 16 + g * 4 + rr;
                float v = acc[i][j][rr] + bv;
                if (OUTF32)
                    ((float*)Cout)[(size_t)row * 768 + col] = v;
                else
                    ((unsigned short*)Cout)[(size_t)row * 768 + col] = f2bf(v);
            }
        }
    }
}

// ---------------------------------------------------------------------------
// Flash attention, bf16 MFMA. grid (32, 24) = (q-blocks, b*h), 256 thr/4 waves.
// Wave w owns q rows q0+w*16..+15. K/Vt staged in swizzled LDS per 64-kv tile.
// ---------------------------------------------------------------------------
__global__ __launch_bounds__(256)
void flash_mfma(const unsigned short* __restrict__ Qb,
                const unsigned short* __restrict__ Kb,
                const unsigned short* __restrict__ Vt,
                unsigned short* __restrict__ AO) {
    __shared__ unsigned short Ks[64 * 64];     // 8 KB  [kv][d]
    __shared__ unsigned short Vs[64 * 64];     // 8 KB  [d][kv]
    __shared__ unsigned short Ps[4 * 16 * 64]; // 8 KB  per-wave P band
    const int tid = threadIdx.x;
    const int w = tid >> 6, l = tid & 63, g = l >> 4, r16 = l & 15;
    const int q0 = blockIdx.x * 64;
    const int b = blockIdx.y / NH, h = blockIdx.y % NH;

    // Q fragments (A operand), held in registers for the whole kernel
    bf16x8 qf[2];
    {
        size_t qrow = (size_t)(b * NQ + q0 + w * 16 + r16);
        #pragma unroll
        for (int kk = 0; kk < 2; ++kk)
            qf[kk] = *(const bf16x8*)(Qb + qrow * DIM + h * HD + kk * 32 + g * 8);
    }

    f32x4 o[4];
    float mrow[4], lrow[4];
    #pragma unroll
    for (int d = 0; d < 4; ++d) o[d] = (f32x4){0.f, 0.f, 0.f, 0.f};
    #pragma unroll
    for (int i = 0; i < 4; ++i) { mrow[i] = -INFINITY; lrow[i] = 0.f; }

    const unsigned short* Kbase = Kb + (size_t)b * NKV * DIM + h * HD;
    const unsigned short* Vbase = Vt + ((size_t)b * DIM + h * HD) * NKV;

    for (int t0 = 0; t0 < NKV; t0 += 64) {
        __syncthreads();   // previous tile's LDS reads complete
        #pragma unroll
        for (int is = 0; is < 2; ++is) {
            int c = is * 256 + tid, r = c >> 3, cc = c & 7;
            int col = ((cc ^ (r & 7)) << 3);
            ld_lds16((char*)Ks + is * 4096 + w * 1024,
                     Kbase + (size_t)(t0 + r) * DIM + col);
            ld_lds16((char*)Vs + is * 4096 + w * 1024,
                     Vbase + (size_t)r * NKV + t0 + col);
        }
        __syncthreads();   // drains vmcnt -> K/V tiles visible

        // S = Q . K^T  (wave's 16 q-rows x 64 kv)
        f32x4 s[4];
        #pragma unroll
        for (int j = 0; j < 4; ++j) {
            s[j] = (f32x4){0.f, 0.f, 0.f, 0.f};
            #pragma unroll
            for (int kk = 0; kk < 2; ++kk) {
                int row = j * 16 + r16;
                bf16x8 kf = *(const bf16x8*)((const char*)Ks + row * 128 +
                              ((kk * 64 + g * 16) ^ ((row & 7) << 4)));
                s[j] = __builtin_amdgcn_mfma_f32_16x16x32_bf16(qf[kk], kf, s[j], 0, 0, 0);
            }
        }

        // online softmax; rows = g*4+i, reduce over 16-lane col group
        float sc[4];
        #pragma unroll
        for (int j = 0; j < 4; ++j) s[j] *= QSCALE;
        #pragma unroll
        for (int i = 0; i < 4; ++i) {
            float mx = fmaxf(fmaxf(s[0][i], s[1][i]), fmaxf(s[2][i], s[3][i]));
            mx = fmaxf(mx, __shfl_xor(mx, 1));
            mx = fmaxf(mx, __shfl_xor(mx, 2));
            mx = fmaxf(mx, __shfl_xor(mx, 4));
            mx = fmaxf(mx, __shfl_xor(mx, 8));
            float mnew = fmaxf(mrow[i], mx);
            float scf = __expf(mrow[i] - mnew);
            float rs = 0.f;
            #pragma unroll
            for (int j = 0; j < 4; ++j) {
                float p = __expf(s[j][i] - mnew);
                s[j][i] = p;
                rs += p;
            }
            rs += __shfl_xor(rs, 1);
            rs += __shfl_xor(rs, 2);
            rs += __shfl_xor(rs, 4);
            rs += __shfl_xor(rs, 8);
            lrow[i] = lrow[i] * scf + rs;
            mrow[i] = mnew;
            sc[i] = scf;
        }
        #pragma unroll
        for (int d = 0; d < 4; ++d)
            #pragma unroll
            for (int i = 0; i < 4; ++i) o[d][i] *= sc[i];

        // P -> LDS (bf16, swizzled), per-wave band
        #pragma unroll
        for (int j = 0; j < 4; ++j)
            #pragma unroll
            for (int i = 0; i < 4; ++i) {
                int row = g * 4 + i;
                int byte = w * 2048 + row * 128 +
                           (((j * 16 + r16) * 2) ^ ((row & 7) << 4));
                *(unsigned short*)((char*)Ps + byte) = f2bf(s[j][i]);
            }

        // O += P . V   (A-frags from Ps, B-frags from Vs)
        bf16x8 pa[2];
        #pragma unroll
        for (int kk = 0; kk < 2; ++kk)
            pa[kk] = *(const bf16x8*)((const char*)Ps + w * 2048 + r16 * 128 +
                      ((kk * 64 + g * 16) ^ ((r16 & 7) << 4)));
        #pragma unroll
        for (int d = 0; d < 4; ++d) {
            #pragma unroll
            for (int kk = 0; kk < 2; ++kk) {
                int vrow = d * 16 + r16;
                bf16x8 vf = *(const bf16x8*)((const char*)Vs + vrow * 128 +
                              ((kk * 64 + g * 16) ^ ((vrow & 7) << 4)));
                o[d] = __builtin_amdgcn_mfma_f32_16x16x32_bf16(pa[kk], vf, o[d], 0, 0, 0);
            }
        }
    }

    #pragma unroll
    for (int i = 0; i < 4; ++i) {
        float inv = 1.f / lrow[i];
        #pragma unroll
        for (int d = 0; d < 4; ++d) {
            size_t row = (size_t)(b * NQ + q0 + w * 16 + g * 4 + i);
            AO[row * DIM + h * HD + d * 16 + r16] = f2bf(o[d][i] * inv);
        }
    }
}

// ---------------------------------------------------------------------------
extern "C" void kernel_launch(void* const* d_in, const int* in_sizes, int n_in,
                              void* d_out, int out_size, void* d_ws, size_t ws_size,
                              hipStream_t stream) {
    const float* words   = (const float*)d_in[0];
    const float* posw    = (const float*)d_in[1];
    const float* consc   = (const float*)d_in[2];
    const float* cross   = (const float*)d_in[3];
    const float* pcross  = (const float*)d_in[4];
    const float* Wq_w    = (const float*)d_in[5];
    const float* Wk_w    = (const float*)d_in[6];
    const float* Wv_w    = (const float*)d_in[7];
    const float* Wq_p    = (const float*)d_in[8];
    const float* Wk_p    = (const float*)d_in[9];
    const float* Wq_c    = (const float*)d_in[10];
    const float* Wk_c    = (const float*)d_in[11];
    const float* latentk = (const float*)d_in[12];
    const float* Wo      = (const float*)d_in[13];
    const float* bo      = (const float*)d_in[14];

    char* arena = (char*)d_ws;
    const size_t ACTB = 6291456;            // bf16 act bytes
    unsigned short* act0 = (unsigned short*)(arena + 0 * ACTB);  // words  -> later pcross
    unsigned short* act1 = (unsigned short*)(arena + 1 * ACTB);  // posw   -> later Kb
    unsigned short* act2 = (unsigned short*)(arena + 2 * ACTB);  // consc  -> later Vt
    unsigned short* act3 = (unsigned short*)(arena + 3 * ACTB);  // cross  -> later AO
    unsigned short* wt   = (unsigned short*)(arena + 4 * ACTB);  // 7 x 1179648 B
    const size_t WTE = 768 * 768;
    unsigned short* qb = (unsigned short*)(arena + 4 * ACTB + 7 * WTE * 2);
    unsigned short* vb = (unsigned short*)((char*)qb + ACTB);
    float* kcv         = (float*)((char*)vb + ACTB);

    unsigned short* pcb = act0;   // pcross bf16 (after Q proj)
    unsigned short* kb  = act1;
    unsigned short* vt  = act2;
    unsigned short* ao  = act3;

    // 1. activations -> bf16 (words, posw, consc, cross)
    convert_acts<<<dim3(3072, 4), dim3(256), 0, stream>>>(words, posw, consc, cross, act0);
    // 2. weights -> bf16 transposed
    conv_w<<<dim3(24, 24, 7), dim3(256), 0, stream>>>(Wq_w, Wq_p, Wq_c, Wk_w, Wk_p, Wv_w, Wo, wt);
    // 3. kc (fp32)
    kc_kernel<<<dim3(3), dim3(256), 0, stream>>>(latentk, Wk_c, kcv);
    // 4. Q = words@Wq_w + posw@Wq_p + consc@Wq_c
    mfma_gemm<3, false><<<dim3(6, 64), dim3(256), 0, stream>>>(
        act0, wt + 0 * WTE, act1, wt + 1 * WTE, act2, wt + 2 * WTE, nullptr, qb);
    // 5. V = cross@Wv_w
    mfma_gemm<1, false><<<dim3(6, 64), dim3(256), 0, stream>>>(
        act3, wt + 5 * WTE, nullptr, nullptr, nullptr, nullptr, nullptr, vb);
    // 6. pcross -> bf16 (into act0, dead after Q proj)
    convert_acts<<<dim3(3072, 1), dim3(256), 0, stream>>>(pcross, nullptr, nullptr, nullptr, pcb);
    // 7. V transpose: vb [4096][768] -> vt [b][768][2048]
    vt_kernel<<<dim3(24, 64, 2), dim3(256), 0, stream>>>(vb, vt);
    // 8. K = cross@Wk_w + pcross@Wk_p + kc
    mfma_gemm<2, false><<<dim3(6, 64), dim3(256), 0, stream>>>(
        act3, wt + 3 * WTE, pcb, wt + 4 * WTE, nullptr, nullptr, kcv, kb);
    // 9. flash attention -> ao
    flash_mfma<<<dim3(32, 24), dim3(256), 0, stream>>>(qb, kb, vt, ao);
    // 10. out = ao@Wo + bo (fp32)
    mfma_gemm<1, true><<<dim3(6, 64), dim3(256), 0, stream>>>(
        ao, wt + 6 * WTE, nullptr, nullptr, nullptr, nullptr, bo, (float*)d_out);
}

// Round 4
// 160.033 us; speedup vs baseline: 6.9042x; 1.4563x over previous
//
#include <hip/hip_runtime.h>
#include <math.h>

#define DIM  768
#define NH   12
#define HD   64
#define NQ   2048
#define NKV  2048
// QSCALE * log2(e) folded into Q projection epilogue
#define QSC_LOG2E 0.18033688011112042f

typedef short bf16x8  __attribute__((ext_vector_type(8)));
typedef float f32x4   __attribute__((ext_vector_type(4)));
typedef float f32x16  __attribute__((ext_vector_type(16)));

__device__ __forceinline__ unsigned short f2bf(float f) {
    unsigned u = __float_as_uint(f);
    unsigned r = (u + 0x7FFFu + ((u >> 16) & 1u)) >> 16;
    return (unsigned short)r;
}

__device__ __forceinline__ unsigned cvtpk_bf16(float a, float b) {
    unsigned r;
    asm("v_cvt_pk_bf16_f32 %0, %1, %2" : "=v"(r) : "v"(a), "v"(b));
    return r;   // lo = bf16(a), hi = bf16(b)
}

// v_permlane32_swap_b32 vdst, vsrc: vdst[32..63] <-> vsrc[0..31].
// With a = pk(regs r,r+1), b = pk(regs r+4,r+5):
//   a' = {a_lanes0-31 | b_lanes0-31}  (low-half word)
//   b' = {a_lanes32-63 | b_lanes32-63} (high-half word)
__device__ __forceinline__ void plswap(unsigned& a, unsigned& b) {
    asm("v_permlane32_swap_b32 %0, %1" : "+v"(a), "+v"(b));
}

__device__ __forceinline__ float vexp2f(float x) {
#if __has_builtin(__builtin_amdgcn_exp2f)
    return __builtin_amdgcn_exp2f(x);
#else
    float r;
    asm("v_exp_f32 %0, %1\ns_nop 0" : "=v"(r) : "v"(x));
    return r;
#endif
}

__device__ __forceinline__ void ld_lds16(void* lds, const void* g) {
    __builtin_amdgcn_global_load_lds(
        (const __attribute__((address_space(1))) unsigned int*)g,
        (__attribute__((address_space(3))) unsigned int*)lds, 16, 0, 0);
}

__device__ __forceinline__ f32x16 z16() {
    f32x16 r;
    #pragma unroll
    for (int e = 0; e < 16; ++e) r[e] = 0.f;
    return r;
}

union PB16 { unsigned u[4]; bf16x8 v; };

// ---------------------------------------------------------------------------
// kc = latent_k @ Wk_c  (fp32), grid 48 x 256
// ---------------------------------------------------------------------------
__global__ __launch_bounds__(256)
void kc2_kernel(const float* __restrict__ latent, const float* __restrict__ Wkc,
                float* __restrict__ kc) {
    __shared__ float red[16][17];
    int tx = threadIdx.x & 15, ty = threadIdx.x >> 4;
    int j = blockIdx.x * 16 + tx;
    float acc = 0.f;
    for (int i = ty * 48; i < ty * 48 + 48; ++i) acc += latent[i] * Wkc[i * DIM + j];
    red[ty][tx] = acc;
    __syncthreads();
    if (ty == 0) {
        float s = 0.f;
        #pragma unroll
        for (int k = 0; k < 16; ++k) s += red[k][tx];
        kc[j] = s;
    }
}

// ---------------------------------------------------------------------------
// fp32 -> bf16, 5 tensors; y<4 -> dstA + y*3145728, y==4 -> dstB
// ---------------------------------------------------------------------------
__global__ __launch_bounds__(256)
void convert_acts(const float* __restrict__ s0, const float* __restrict__ s1,
                  const float* __restrict__ s2, const float* __restrict__ s3,
                  const float* __restrict__ s4,
                  unsigned short* __restrict__ dstA, unsigned short* __restrict__ dstB) {
    const float* srcs[5] = {s0, s1, s2, s3, s4};
    int y = blockIdx.y;
    const float* s = srcs[y];
    unsigned short* d = (y < 4) ? (dstA + (size_t)y * 3145728) : dstB;
    size_t i = ((size_t)blockIdx.x * 256 + threadIdx.x) * 4;
    float4 v = *(const float4*)(s + i);
    ushort4 o;
    o.x = f2bf(v.x); o.y = f2bf(v.y); o.z = f2bf(v.z); o.w = f2bf(v.w);
    *(ushort4*)(d + i) = o;
}

// ---------------------------------------------------------------------------
// weight transpose+convert: W fp32 [768][768] -> Wt bf16 [n][k]
// ---------------------------------------------------------------------------
__global__ __launch_bounds__(256)
void conv_w(const float* __restrict__ w0, const float* __restrict__ w1,
            const float* __restrict__ w2, const float* __restrict__ w3,
            const float* __restrict__ w4, const float* __restrict__ w5,
            const float* __restrict__ w6, unsigned short* __restrict__ dst) {
    __shared__ float t[32][33];
    const float* Ws[7] = {w0, w1, w2, w3, w4, w5, w6};
    const float* W = Ws[blockIdx.z];
    unsigned short* D = dst + (size_t)blockIdx.z * (768 * 768);
    int r0 = blockIdx.y * 32, c0 = blockIdx.x * 32;
    int tx = threadIdx.x & 31, ty = threadIdx.x >> 5;
    #pragma unroll
    for (int yy = 0; yy < 4; ++yy)
        t[ty * 4 + yy][tx] = W[(size_t)(r0 + ty * 4 + yy) * 768 + c0 + tx];
    __syncthreads();
    #pragma unroll
    for (int yy = 0; yy < 4; ++yy)
        D[(size_t)(c0 + ty * 4 + yy) * 768 + r0 + tx] = f2bf(t[tx][ty * 4 + yy]);
}

// ---------------------------------------------------------------------------
// MFMA GEMM, 2-phase double-buffered. Tile 64(M)x128(N), BK=64, 4 waves.
// MODE: 0 bf16 out (+opt fp32 bias), 1 f32 out +bias, 2 bf16 out *scale,
//       3 bf16 transposed out into Vt[b][768][2048]
// ---------------------------------------------------------------------------
template<int NPAIR, int MODE>
__global__ __launch_bounds__(256)
void mfma_gemm(const unsigned short* __restrict__ A0, const unsigned short* __restrict__ B0,
               const unsigned short* __restrict__ A1, const unsigned short* __restrict__ B1,
               const unsigned short* __restrict__ A2, const unsigned short* __restrict__ B2,
               const float* __restrict__ bias, float scale, void* __restrict__ Cout) {
    __shared__ unsigned short As[2][64 * 64];    // 2 x 8 KB
    __shared__ unsigned short Bs[2][128 * 64];   // 2 x 16 KB
    const int tid = threadIdx.x;
    const int w = tid >> 6, l = tid & 63, g = l >> 4, r16 = l & 15;

    // XCD-bijective swizzle: 384 blocks = 8 XCD * 48
    int o_lin = blockIdx.x + 6 * blockIdx.y;
    int wl = (o_lin & 7) * 48 + (o_lin >> 3);
    int bx = wl % 6, by = wl / 6;
    const int n0 = bx * 128, m0 = by * 64;

    const unsigned short* Alist[3] = {A0, A1, A2};
    const unsigned short* Blist[3] = {B0, B1, B2};

    f32x4 acc[4][2];
    #pragma unroll
    for (int i = 0; i < 4; ++i)
        #pragma unroll
        for (int j = 0; j < 2; ++j) acc[i][j] = (f32x4){0.f, 0.f, 0.f, 0.f};

#define GSTAGE(BUFI, AP, BP, K0) { \
    _Pragma("unroll") \
    for (int is = 0; is < 2; ++is) { \
        int u = is * 256 + tid, r = u >> 3, cc = u & 7; \
        int col = ((cc ^ (r & 7)) << 3); \
        ld_lds16((char*)As[BUFI] + is * 4096 + w * 1024, \
                 (AP) + (size_t)(m0 + r) * 768 + (K0) + col); } \
    _Pragma("unroll") \
    for (int is = 0; is < 4; ++is) { \
        int u = is * 256 + tid, r = u >> 3, cc = u & 7; \
        int col = ((cc ^ (r & 7)) << 3); \
        ld_lds16((char*)Bs[BUFI] + is * 4096 + w * 1024, \
                 (BP) + (size_t)(n0 + r) * 768 + (K0) + col); } }

    const int NSTEPS = NPAIR * 12;
    int pn = 0, kn = 0;           // indices of the NEXT step to stage
    GSTAGE(0, Alist[0], Blist[0], 0);
    kn = 64; if (kn == 768) { kn = 0; ++pn; }
    __syncthreads();

    #pragma unroll 1
    for (int st = 0; st < NSTEPS; ++st) {
        int cur = st & 1;
        if (st + 1 < NSTEPS) {
            GSTAGE(cur ^ 1, Alist[pn], Blist[pn], kn);
            kn += 64; if (kn == 768) { kn = 0; ++pn; }
        }
        const char* Ab = (const char*)As[cur];
        const char* Bb = (const char*)Bs[cur];
        #pragma unroll
        for (int kk = 0; kk < 2; ++kk) {
            bf16x8 af[4], bf[2];
            #pragma unroll
            for (int i = 0; i < 4; ++i) {
                int row = i * 16 + r16;
                af[i] = *(const bf16x8*)(Ab + row * 128 +
                          ((kk * 64 + g * 16) ^ ((row & 7) << 4)));
            }
            #pragma unroll
            for (int j = 0; j < 2; ++j) {
                int row = w * 32 + j * 16 + r16;
                bf[j] = *(const bf16x8*)(Bb + row * 128 +
                          ((kk * 64 + g * 16) ^ ((row & 7) << 4)));
            }
            #pragma unroll
            for (int i = 0; i < 4; ++i)
                #pragma unroll
                for (int j = 0; j < 2; ++j)
                    acc[i][j] = __builtin_amdgcn_mfma_f32_16x16x32_bf16(
                        af[i], bf[j], acc[i][j], 0, 0, 0);
        }
        __syncthreads();
    }
#undef GSTAGE

    #pragma unroll
    for (int i = 0; i < 4; ++i) {
        #pragma unroll
        for (int j = 0; j < 2; ++j) {
            int col = n0 + w * 32 + j * 16 + r16;
            float bv = ((MODE == 0 && bias) || MODE == 1) ? bias[col] : 0.f;
            #pragma unroll
            for (int rr = 0; rr < 4; ++rr) {
                int row = m0 + i * 16 + g * 4 + rr;
                float v = acc[i][j][rr];
                if (MODE == 2) v *= scale;
                v += bv;
                if (MODE == 1) {
                    ((float*)Cout)[(size_t)row * 768 + col] = v;
                } else if (MODE == 3) {
                    int bb = row >> 11, q = row & 2047;
                    ((unsigned short*)Cout)[(size_t)(bb * 768 + col) * 2048 + q] = f2bf(v);
                } else {
                    ((unsigned short*)Cout)[(size_t)row * 768 + col] = f2bf(v);
                }
            }
        }
    }
}

// ---------------------------------------------------------------------------
// Flash attention: swapped QK^T, in-register softmax (log2 domain), 32x32 MFMA.
// 4 waves x 32 q-rows = 128 q/block; grid (16, 24). K/V^T dbuf in swizzled LDS.
// ---------------------------------------------------------------------------
__global__ __launch_bounds__(256)
void flash2(const unsigned short* __restrict__ Qb,
            const unsigned short* __restrict__ Kb,
            const unsigned short* __restrict__ Vt,
            unsigned short* __restrict__ AO) {
    __shared__ unsigned short KV[2][2][4096];  // [buf][K|Vt][64*64], 32 KB
    const int tid = threadIdx.x;
    const int w = tid >> 6, l = tid & 63, lo = l & 31, hi = l >> 5;

    // XCD-bijective swizzle: each bh (16 q-blocks) stays on one XCD
    int o_lin = blockIdx.x + 16 * blockIdx.y;
    int wl = (o_lin & 7) * 48 + (o_lin >> 3);
    int qi = wl & 15, bh = wl >> 4;
    int b = bh / NH, h = bh % NH;
    int q0 = qi * 128;

    // Q B-fragments, scaled upstream by QSC_LOG2E
    bf16x8 qf[4];
    {
        const unsigned short* Qrow =
            Qb + (size_t)(b * NQ + q0 + w * 32 + lo) * DIM + h * HD + hi * 8;
        #pragma unroll
        for (int kc = 0; kc < 4; ++kc) qf[kc] = *(const bf16x8*)(Qrow + kc * 16);
    }

    f32x16 o0 = z16(), o1 = z16();
    float m = -3.0e38f, lsum = 0.f;

    const unsigned short* Kbase = Kb + (size_t)(b * NKV) * DIM + h * HD;
    const unsigned short* Vbase = Vt + ((size_t)b * DIM + h * HD) * NKV;

#define FSTAGE(BUFI, T0) { \
    _Pragma("unroll") \
    for (int is = 0; is < 2; ++is) { \
        int u = is * 256 + tid, r = u >> 3, cc = u & 7; \
        int col = ((cc ^ (r & 7)) << 3); \
        ld_lds16((char*)KV[BUFI][0] + is * 4096 + w * 1024, \
                 Kbase + (size_t)((T0) + r) * 768 + col); \
        ld_lds16((char*)KV[BUFI][1] + is * 4096 + w * 1024, \
                 Vbase + (size_t)r * 2048 + (T0) + col); } }

    FSTAGE(0, 0);
    __syncthreads();

    #pragma unroll 1
    for (int t = 0; t < 32; ++t) {
        int cur = t & 1;
        if (t < 31) FSTAGE(cur ^ 1, (t + 1) * 64);

        const char* Kp = (const char*)KV[cur][0];
        const char* Vp = (const char*)KV[cur][1];

        // S^T = K . Q^T : lane owns one q-row, 32 kv values (16 per tile)
        f32x16 s0 = z16(), s1 = z16();
        #pragma unroll
        for (int kc = 0; kc < 4; ++kc) {
            int r0 = lo, r1 = 32 + lo;
            bf16x8 k0 = *(const bf16x8*)(Kp + r0 * 128 +
                          ((kc * 32 + hi * 16) ^ ((r0 & 7) << 4)));
            bf16x8 k1 = *(const bf16x8*)(Kp + r1 * 128 +
                          ((kc * 32 + hi * 16) ^ ((r1 & 7) << 4)));
            s0 = __builtin_amdgcn_mfma_f32_32x32x16_bf16(k0, qf[kc], s0, 0, 0, 0);
            s1 = __builtin_amdgcn_mfma_f32_32x32x16_bf16(k1, qf[kc], s1, 0, 0, 0);
        }

        // in-register softmax (log2 domain), lane pair (l, l^32) shares a q-row
        float a8[8];
        #pragma unroll
        for (int e = 0; e < 8; ++e)
            a8[e] = fmaxf(fmaxf(s0[e], s0[e + 8]), fmaxf(s1[e], s1[e + 8]));
        #pragma unroll
        for (int e = 0; e < 4; ++e) a8[e] = fmaxf(a8[e], a8[e + 4]);
        float pm = fmaxf(fmaxf(a8[0], a8[1]), fmaxf(a8[2], a8[3]));
        pm = fmaxf(pm, __shfl_xor(pm, 32));

        if (__any(pm > m + 10.f)) {           // defer-max (T13)
            float mn = fmaxf(m, pm);
            float sc = vexp2f(m - mn);
            lsum *= sc;
            #pragma unroll
            for (int e = 0; e < 16; ++e) { o0[e] *= sc; o1[e] *= sc; }
            m = mn;
        }

        #pragma unroll
        for (int e = 0; e < 16; ++e) {
            s0[e] = vexp2f(s0[e] - m);
            s1[e] = vexp2f(s1[e] - m);
        }

        float b8[8];
        #pragma unroll
        for (int e = 0; e < 8; ++e)
            b8[e] = (s0[e] + s0[e + 8]) + (s1[e] + s1[e + 8]);
        float rs = ((b8[0] + b8[1]) + (b8[2] + b8[3])) +
                   ((b8[4] + b8[5]) + (b8[6] + b8[7]));
        rs += __shfl_xor(rs, 32);
        lsum += rs;

        // P -> bf16 B-fragments via cvt_pk + permlane32_swap.
        // aX = pk(regs 2X,2X+1) [kv low-quad], bX = pk(regs 2X+4,2X+5) [high-quad];
        // plswap(a,b): a'={a_lo|b_lo} -> word e(0,1)/(2,3); b'={a_hi|b_hi} -> word e(4,5)/(6,7)
        PB16 pb[4];
        #pragma unroll
        for (int cc = 0; cc < 2; ++cc) {
            unsigned a0 = cvtpk_bf16(s0[cc * 8 + 0], s0[cc * 8 + 1]);
            unsigned a1 = cvtpk_bf16(s0[cc * 8 + 2], s0[cc * 8 + 3]);
            unsigned b0 = cvtpk_bf16(s0[cc * 8 + 4], s0[cc * 8 + 5]);
            unsigned b1 = cvtpk_bf16(s0[cc * 8 + 6], s0[cc * 8 + 7]);
            plswap(a0, b0);
            plswap(a1, b1);
            pb[cc].u[0] = a0; pb[cc].u[1] = a1; pb[cc].u[2] = b0; pb[cc].u[3] = b1;
            unsigned c0 = cvtpk_bf16(s1[cc * 8 + 0], s1[cc * 8 + 1]);
            unsigned c1 = cvtpk_bf16(s1[cc * 8 + 2], s1[cc * 8 + 3]);
            unsigned d0 = cvtpk_bf16(s1[cc * 8 + 4], s1[cc * 8 + 5]);
            unsigned d1 = cvtpk_bf16(s1[cc * 8 + 6], s1[cc * 8 + 7]);
            plswap(c0, d0);
            plswap(c1, d1);
            pb[2 + cc].u[0] = c0; pb[2 + cc].u[1] = c1;
            pb[2 + cc].u[2] = d0; pb[2 + cc].u[3] = d1;
        }

        // O^T += V^T . P^T
        #pragma unroll
        for (int c = 0; c < 4; ++c) {
            int r0 = lo, r1 = 32 + lo;
            bf16x8 v0 = *(const bf16x8*)(Vp + r0 * 128 +
                          ((c * 32 + hi * 16) ^ ((r0 & 7) << 4)));
            bf16x8 v1 = *(const bf16x8*)(Vp + r1 * 128 +
                          ((c * 32 + hi * 16) ^ ((r1 & 7) << 4)));
            o0 = __builtin_amdgcn_mfma_f32_32x32x16_bf16(v0, pb[c].v, o0, 0, 0, 0);
            o1 = __builtin_amdgcn_mfma_f32_32x32x16_bf16(v1, pb[c].v, o1, 0, 0, 0);
        }
        __syncthreads();
    }
#undef FSTAGE

    // epilogue: O^T regs -> LDS (per-wave 4KB, swizzled) -> coalesced global
    float inv = 1.f / lsum;
    char* eb = (char*)KV + w * 4096;
    #pragma unroll
    for (int r = 0; r < 16; r += 2) {
        int d0 = (r & 3) + 8 * (r >> 2) + 4 * hi;       // pair d0, d0+1
        *(unsigned*)(eb + lo * 128 + ((2 * d0) ^ ((lo & 7) << 4))) =
            cvtpk_bf16(o0[r] * inv, o0[r + 1] * inv);
        int d1 = 32 + d0;
        *(unsigned*)(eb + lo * 128 + ((2 * d1) ^ ((lo & 7) << 4))) =
            cvtpk_bf16(o1[r] * inv, o1[r + 1] * inv);
    }
    int q2 = l >> 1, h2 = l & 1;
    size_t grow = (size_t)(b * NQ + q0 + w * 32 + q2) * DIM + h * HD + h2 * 32;
    #pragma unroll
    for (int c = 0; c < 4; ++c) {
        uint4 vv = *(const uint4*)(eb + q2 * 128 + ((h2 * 64 + c * 16) ^ ((q2 & 7) << 4)));
        *(uint4*)(AO + grow + c * 8) = vv;
    }
}

// ---------------------------------------------------------------------------
extern "C" void kernel_launch(void* const* d_in, const int* in_sizes, int n_in,
                              void* d_out, int out_size, void* d_ws, size_t ws_size,
                              hipStream_t stream) {
    const float* words   = (const float*)d_in[0];
    const float* posw    = (const float*)d_in[1];
    const float* consc   = (const float*)d_in[2];
    const float* cross   = (const float*)d_in[3];
    const float* pcross  = (const float*)d_in[4];
    const float* Wq_w    = (const float*)d_in[5];
    const float* Wk_w    = (const float*)d_in[6];
    const float* Wv_w    = (const float*)d_in[7];
    const float* Wq_p    = (const float*)d_in[8];
    const float* Wk_p    = (const float*)d_in[9];
    const float* Wq_c    = (const float*)d_in[10];
    const float* Wk_c    = (const float*)d_in[11];
    const float* latentk = (const float*)d_in[12];
    const float* Wo      = (const float*)d_in[13];
    const float* bo      = (const float*)d_in[14];

    char* arena = (char*)d_ws;
    const size_t ACTB = 6291456;                       // one bf16 activation slab
    unsigned short* act0 = (unsigned short*)(arena);            // words  -> AO
    unsigned short* act1 = (unsigned short*)(arena + ACTB);     // posw   -> K
    unsigned short* act2 = (unsigned short*)(arena + 2 * ACTB); // consc  -> Vt
    unsigned short* act3 = (unsigned short*)(arena + 3 * ACTB); // cross
    unsigned short* wt   = (unsigned short*)(arena + 4 * ACTB); // 7 x 768x768 bf16
    const size_t WTE = 768 * 768;
    unsigned short* qb  = (unsigned short*)(arena + 4 * ACTB + 7 * WTE * 2);
    unsigned short* pcb = (unsigned short*)((char*)qb + ACTB);  // pcross bf16
    float* kcv          = (float*)((char*)pcb + ACTB);

    unsigned short* kb = act1;
    unsigned short* vt = act2;
    unsigned short* ao = act0;

    convert_acts<<<dim3(3072, 5), dim3(256), 0, stream>>>(
        words, posw, consc, cross, pcross, act0, pcb);
    conv_w<<<dim3(24, 24, 7), dim3(256), 0, stream>>>(
        Wq_w, Wq_p, Wq_c, Wk_w, Wk_p, Wv_w, Wo, wt);
    kc2_kernel<<<dim3(48), dim3(256), 0, stream>>>(latentk, Wk_c, kcv);

    // Q = (words@Wq_w + posw@Wq_p + consc@Wq_c) * QSC_LOG2E
    mfma_gemm<3, 2><<<dim3(6, 64), dim3(256), 0, stream>>>(
        act0, wt + 0 * WTE, act1, wt + 1 * WTE, act2, wt + 2 * WTE,
        nullptr, QSC_LOG2E, qb);
    // Vt[b][768][2048] = (cross@Wv_w)^T
    mfma_gemm<1, 3><<<dim3(6, 64), dim3(256), 0, stream>>>(
        act3, wt + 5 * WTE, nullptr, nullptr, nullptr, nullptr,
        nullptr, 1.f, vt);
    // K = cross@Wk_w + pcross@Wk_p + kc
    mfma_gemm<2, 0><<<dim3(6, 64), dim3(256), 0, stream>>>(
        act3, wt + 3 * WTE, pcb, wt + 4 * WTE, nullptr, nullptr,
        kcv, 1.f, kb);
    // flash attention
    flash2<<<dim3(16, 24), dim3(256), 0, stream>>>(qb, kb, vt, ao);
    // out = ao@Wo + bo (fp32)
    mfma_gemm<1, 1><<<dim3(6, 64), dim3(256), 0, stream>>>(
        ao, wt + 6 * WTE, nullptr, nullptr, nullptr, nullptr,
        bo, 1.f, (float*)d_out);
}